// Round 12
// baseline (252.550 us; speedup 1.0000x reference)
//
#include <hip/hip_runtime.h>

#define NA 50000
#define NP 50000
#define NE 800000
#define D 128
#define OUTD 32
#define NSEG 150000
#define DD (D * D)
#define NCH 196        // chunks per relation (4096 edges each)
#define NBK 588        // 3 relations x 196 buckets (dst>>8)
#define CHE 4096       // edges per chunk
#define CAP2 4608      // fixed bucket capacity (mean 4096 + 8 sigma)
#define ZROW 50000     // index of the all-zeros pad row

typedef float f32x4 __attribute__((ext_vector_type(4)));
typedef short s16x8 __attribute__((ext_vector_type(8)));

__device__ __forceinline__ ushort f2b(float f) {
    uint x = __float_as_uint(f);
    x += ((x >> 16) & 1u) + 0x7fffu;   // round-to-nearest-even
    return (ushort)(x >> 16);
}

// ---------------- K1: cvt_x | prep_w | zero-pad rows | bucket-scatter ----------------

#define CVT_BLOCKS 12500   // 3.2M float4
#define PREP_BLOCKS 466    // 465 weight-prep + 1 zero-pad-rows
#define SCAT_BLOCKS NBK

__global__ __launch_bounds__(256) void front2(
    const float* __restrict__ xa, const float* __restrict__ xp,
    ushort* __restrict__ oa, ushort* __restrict__ op,
    const float* __restrict__ Wl, const float* __restrict__ Wr,
    const float* __restrict__ linW, const float* __restrict__ bl,
    ushort* __restrict__ wt, float* __restrict__ bsum_p,
    ushort* __restrict__ p1b,
    const int* __restrict__ sw, const int* __restrict__ dw,
    const int* __restrict__ sc_, const int* __restrict__ dc,
    const int* __restrict__ swb, const int* __restrict__ dwb,
    int* __restrict__ cursor, uint* __restrict__ bucketed)
{
    __shared__ uint recbuf[CHE];       // 16 KB chunk stash
    __shared__ int hist[NCH], gbase[NCH], cnt2[NCH];
    int b = blockIdx.x, t = threadIdx.x;
    if (b < CVT_BLOCKS) {
        int i = b * 256 + t;
        const int per = NA * D / 4;
        const float* src; ushort* dst; int li;
        if (i < per) { src = xa; dst = oa; li = i; }
        else { src = xp; dst = op; li = i - per; }
        float4 v = *(const float4*)&src[(size_t)li * 4];
        ushort4 o;
        o.x = f2b(v.x); o.y = f2b(v.y); o.z = f2b(v.z); o.w = f2b(v.w);
        *(ushort4*)&dst[(size_t)li * 4] = o;
    } else if (b < CVT_BLOCKS + PREP_BLOCKS) {
        int b2 = b - CVT_BLOCKS;
        if (b2 < 448) {
            int job = b2 >> 6;
            int idx = (b2 & 63) * 256 + t;
            int n = idx >> 7, k = idx & 127;
            const float* src;
            float add = 0.f;
            switch (job) {
                case 0: src = Wl + 0 * DD; break;
                case 1: src = Wl + 2 * DD; break;
                case 2: src = Wr + 0 * DD; add = Wr[2 * DD + k * D + n]; break;
                case 3: src = Wl + 1 * DD; break;
                case 4: src = Wr + 1 * DD; break;
                case 5: src = Wl + 4 * DD; break;
                default: src = Wr + 4 * DD; break;
            }
            wt[(size_t)job * DD + idx] = f2b(src[k * D + n] + add);
        } else if (b2 < 464) {
            int idx = (b2 - 448) * 256 + t;    // linW^T: n<32, k<128
            int n = idx >> 7, k = idx & 127;
            wt[(size_t)7 * DD + idx] = f2b(linW[k * OUTD + n]);
        } else if (b2 == 464) {
            if (t < D) bsum_p[t] = bl[t] + bl[2 * D + t];
        } else {
            // zero the pad rows (index ZROW) of oa, op, p1b
            if (t < 64)       ((uint*)(oa + (size_t)ZROW * D))[t] = 0;
            else if (t < 128) ((uint*)(op + (size_t)ZROW * D))[t - 64] = 0;
            else if (t < 192) ((uint*)(p1b + (size_t)ZROW * D))[t - 128] = 0;
        }
    } else {
        int hb = b - CVT_BLOCKS - PREP_BLOCKS;
        int r = hb / NCH, c = hb % NCH;
        const int* sp = (r == 0) ? sw : ((r == 1) ? sc_ : swb);
        const int* dp = (r == 0) ? dw : ((r == 1) ? dc : dwb);
        for (int i = t; i < NCH; i += 256) { hist[i] = 0; cnt2[i] = 0; }
        __syncthreads();
        int base = c * CHE;
#pragma unroll
        for (int i = 0; i < 16; ++i) {
            int e = base + i * 256 + t;
            uint rec = 0xFFFFFFFFu;
            if (e < NE) {
                int d = dp[e], s = sp[e];
                rec = ((uint)d << 16) | (uint)s;
                atomicAdd(&hist[d >> 8], 1);
            }
            recbuf[i * 256 + t] = rec;
        }
        __syncthreads();
        for (int i = t; i < NCH; i += 256)
            gbase[i] = (r * NCH + i) * CAP2 + atomicAdd(&cursor[r * NCH + i], hist[i]);
        __syncthreads();
#pragma unroll
        for (int i = 0; i < 16; ++i) {
            uint rec = recbuf[i * 256 + t];
            if (rec != 0xFFFFFFFFu) {
                int dg = rec >> 24;             // (d>>8), d<50000<2^16
                int rk = atomicAdd(&cnt2[dg], 1);
                bucketed[gbase[dg] + rk] = rec;
            }
        }
    }
}

// ---------------- K2: within-bucket sort by dst low byte -> csr16 + rowptr + cntd ----------------

__global__ __launch_bounds__(256) void bucket_sort2(
    const uint* __restrict__ bucketed, const int* __restrict__ cursor,
    ushort* __restrict__ csr16, int* __restrict__ rowptr, int* __restrict__ cntd)
{
    __shared__ int h[256], bb[256], c3[256];
    int gd = blockIdx.x, t = threadIdx.x;
    int r = gd / NCH, hb = gd % NCH;
    int beg = gd * CAP2;
    int n = cursor[gd];
    h[t] = 0; c3[t] = 0;
    __syncthreads();
    for (int i = t; i < n; i += 256)
        atomicAdd(&h[(bucketed[beg + i] >> 16) & 255], 1);
    __syncthreads();
    if (t < 64) {
        int carry = 0;
#pragma unroll
        for (int rnd = 0; rnd < 4; ++rnd) {
            int idx = rnd * 64 + t;
            int v = h[idx], x = v;
#pragma unroll
            for (int off = 1; off < 64; off <<= 1) {
                int y = __shfl_up(x, off, 64);
                if (t >= off) x += y;
            }
            bb[idx] = carry + x - v;
            carry += __shfl(x, 63, 64);
        }
    }
    __syncthreads();
    {
        int dst = hb * 256 + t;
        if (dst < 50000) {
            rowptr[r * 50000 + dst] = beg + bb[t];
            cntd[r * 50000 + dst] = h[t];
        }
    }
    for (int i = t; i < n; i += 256) {
        uint rec = bucketed[beg + i];
        int low = (rec >> 16) & 255;
        int rk = atomicAdd(&c3[low], 1);
        csr16[beg + bb[low] + rk] = (ushort)(rec & 0xffffu);
    }
}

// ---------------- gather-mean (r8 core): zero-row pad + v_dot2_f32_bf16 ----------------

#define DOT2(a, u, m) asm("v_dot2_f32_bf16 %0, %1, %2, %0" : "+v"(a) : "v"(u), "v"(m))

__device__ __forceinline__ void gather_node(
    const ushort* __restrict__ x, const ushort* __restrict__ bk, int n,
    int l, int g, int c, ushort* __restrict__ outp)
{
    float acc[8];
#pragma unroll
    for (int k = 0; k < 8; ++k) acc[k] = 0.f;
    const uint mlo = 0x00003f80u;   // bf16 (1.0, 0)
    const uint mhi = 0x3f800000u;   // bf16 (0, 1.0)
    const uint cb = (uint)c * 16;   // byte offset within row

    for (int base = 0; base < n; base += 64) {
        int rem = n - base;
        int m = rem > 64 ? 64 : rem;
        int idx = (l < m) ? (int)bk[base + l] : ZROW;
        int mceil = (m + 3) & ~3;
#pragma unroll 4
        for (int j = 0; j < mceil; j += 4) {
            int row = __shfl(idx, j + g, 64);
            uint4 u = *(const uint4*)((const char*)x + (((uint)row << 8) + cb));
            DOT2(acc[0], u.x, mlo); DOT2(acc[1], u.x, mhi);
            DOT2(acc[2], u.y, mlo); DOT2(acc[3], u.y, mhi);
            DOT2(acc[4], u.z, mlo); DOT2(acc[5], u.z, mhi);
            DOT2(acc[6], u.w, mlo); DOT2(acc[7], u.w, mhi);
        }
    }
#pragma unroll
    for (int k = 0; k < 8; ++k) {
        acc[k] += __shfl_xor(acc[k], 16, 64);
        acc[k] += __shfl_xor(acc[k], 32, 64);
    }
    if (g == 0) {
        float scl = (n > 0) ? 1.0f / (float)n : 0.f;
        uint4 o;
        o.x = (uint)f2b(acc[0] * scl) | ((uint)f2b(acc[1] * scl) << 16);
        o.y = (uint)f2b(acc[2] * scl) | ((uint)f2b(acc[3] * scl) << 16);
        o.z = (uint)f2b(acc[4] * scl) | ((uint)f2b(acc[5] * scl) << 16);
        o.w = (uint)f2b(acc[6] * scl) | ((uint)f2b(acc[7] * scl) << 16);
        *(uint4*)&outp[c * 8] = o;
    }
}

// ---------------- gather3 v5: relation->XCD partitioning ----------------
// blockIdx round-robins over XCDs (b&7). Steer writes-relation blocks (source
// xb_a) to XCDs {0,1,2}, paper-source blocks (cites+wb) to XCDs {3..7}: each
// XCD's L2 then pulls only ONE 12.8 MB source matrix instead of both ->
// compulsory HBM traffic halves (205 -> ~102 MB). Pure perf heuristic; the
// node mapping is exact and correctness never depends on XCD placement.

__global__ __launch_bounds__(256) void gather3(
    const ushort* __restrict__ xa, const ushort* __restrict__ xp,
    const int* __restrict__ rowptr, const int* __restrict__ cntd,
    const ushort* __restrict__ csr16, ushort* __restrict__ agg3)
{
    int b = blockIdx.x;
    int xcd = b & 7, grp = b >> 3;
    int wv = threadIdx.x >> 6;
    int l = threadIdx.x & 63;
    int wid;
    const ushort* x;
    if (xcd < 3) {                 // writes relation: src = authors
        int ord = grp * 3 + xcd;
        if (ord >= 12500) return;
        wid = ord * 4 + wv;        // [0, 50000)
        x = xa;
    } else {                       // cites + written_by: src = papers
        int ord = grp * 5 + (xcd - 3);
        if (ord >= 25000) return;
        wid = 50000 + ord * 4 + wv; // [50000, 150000)
        x = xp;
    }
    int beg = __builtin_amdgcn_readfirstlane(rowptr[wid]);
    int n = __builtin_amdgcn_readfirstlane(cntd[wid]);
    gather_node(x, csr16 + beg, n, l, l >> 4, l & 15,
                agg3 + (size_t)wid * D);
}

__global__ __launch_bounds__(256) void gather_l1(
    const ushort* __restrict__ x, const int* __restrict__ rowptr,
    const int* __restrict__ cntd, const ushort* __restrict__ csr16,
    ushort* __restrict__ out)
{
    int wid = (blockIdx.x * 256 + threadIdx.x) >> 6;
    if (wid >= NA) return;
    int l = threadIdx.x & 63;
    int beg = __builtin_amdgcn_readfirstlane(rowptr[100000 + wid]);
    int n = __builtin_amdgcn_readfirstlane(cntd[100000 + wid]);
    gather_node(x, csr16 + beg, n, l, l >> 4, l & 15,
                out + (size_t)wid * D);
}

// ---------------- MFMA bf16 GEMM core ----------------

#define LDA 136

__device__ __forceinline__ void gemm_core(
    ushort* As, f32x4 (&acc)[2][4],
    const ushort* __restrict__ A0, const ushort* __restrict__ WT0,
    const ushort* __restrict__ A1, const ushort* __restrict__ WT1,
    const ushort* __restrict__ A2, const ushort* __restrict__ WT2,
    int nseg, int brow, int M)
{
    const int t = threadIdx.x;
    const int w = t >> 6;
    const int l = t & 63;
    const int wr = w >> 1, wc = w & 1;
    const int l15 = l & 15, l4 = l >> 4;

    for (int s = 0; s < nseg; ++s) {
        const ushort* A = (s == 0) ? A0 : ((s == 1) ? A1 : A2);
        const ushort* WT = (s == 0) ? WT0 : ((s == 1) ? WT1 : WT2);

        if (s) __syncthreads();
#pragma unroll
        for (int it = 0; it < 4; ++it) {
            int f = it * 256 + t;
            int row = f >> 4, cc = f & 15;
            int grow = brow + row;
            float4 v = make_float4(0.f, 0.f, 0.f, 0.f);
            if (grow < M) v = *(const float4*)&A[(size_t)grow * D + cc * 8];
            *(float4*)&As[row * LDA + cc * 8] = v;
        }
        s16x8 Bf[4][4];
#pragma unroll
        for (int ni = 0; ni < 4; ++ni)
#pragma unroll
            for (int ks = 0; ks < 4; ++ks)
                Bf[ni][ks] = *(const s16x8*)&WT[(size_t)(wc * 64 + ni * 16 + l15) * D + ks * 32 + l4 * 8];
        __syncthreads();

#pragma unroll
        for (int ks = 0; ks < 4; ++ks) {
            s16x8 af[2];
#pragma unroll
            for (int mi = 0; mi < 2; ++mi)
                af[mi] = *(const s16x8*)&As[(wr * 32 + mi * 16 + l15) * LDA + ks * 32 + l4 * 8];
#pragma unroll
            for (int mi = 0; mi < 2; ++mi)
#pragma unroll
                for (int ni = 0; ni < 4; ++ni)
                    acc[mi][ni] = __builtin_amdgcn_mfma_f32_16x16x32_bf16(
                        af[mi], Bf[ni][ks], acc[mi][ni], 0, 0, 0);
        }
    }
}

// both layer-0 GEMMs in one dispatch
__global__ __launch_bounds__(256) void gemm_pair(
    const ushort* __restrict__ agg3, const ushort* __restrict__ xb_p,
    const ushort* __restrict__ xb_a, const ushort* __restrict__ wt,
    const float* __restrict__ bsum_p, const float* __restrict__ bl,
    ushort* __restrict__ p1b, ushort* __restrict__ a1b)
{
    __shared__ ushort As[64 * LDA];
    const int t = threadIdx.x;
    const int w = t >> 6;
    const int l = t & 63;
    const int wr = w >> 1, wc = w & 1;
    const int l15 = l & 15, l4 = l >> 4;

    f32x4 acc[2][4];
#pragma unroll
    for (int i = 0; i < 2; ++i)
#pragma unroll
        for (int j = 0; j < 4; ++j) acc[i][j] = (f32x4){0.f, 0.f, 0.f, 0.f};

    bool isP = blockIdx.x < 782;
    int bIdx = isP ? blockIdx.x : blockIdx.x - 782;
    int brow = bIdx * 64;
    const float* bias;
    ushort* C;
    if (isP) {
        gemm_core(As, acc, agg3, wt + 0 * DD, agg3 + (size_t)50000 * D, wt + 1 * DD,
                  xb_p, wt + 2 * DD, 3, brow, NP);
        bias = bsum_p; C = p1b;
    } else {
        gemm_core(As, acc, agg3 + (size_t)100000 * D, wt + 3 * DD, xb_a, wt + 4 * DD,
                  nullptr, nullptr, 2, brow, NA);
        bias = bl + 1 * D; C = a1b;
    }

#pragma unroll
    for (int mi = 0; mi < 2; ++mi) {
#pragma unroll
        for (int ni = 0; ni < 4; ++ni) {
            int col = wc * 64 + ni * 16 + l15;
            float bb = bias[col];
#pragma unroll
            for (int r = 0; r < 4; ++r) {
                int grow = brow + wr * 32 + mi * 16 + l4 * 4 + r;
                if (grow >= 50000) continue;
                float v = acc[mi][ni][r] + bb;
                v = v > 0.f ? v : 0.01f * v;
                C[(size_t)grow * D + col] = f2b(v);
            }
        }
    }
}

// layer-1 author GEMM with fused final projection
__global__ __launch_bounds__(256) void gemm_final(
    const ushort* __restrict__ A0, const ushort* __restrict__ WT0,
    const ushort* __restrict__ A1, const ushort* __restrict__ WT1,
    const float* __restrict__ bias,
    const ushort* __restrict__ linWT, const float* __restrict__ linb,
    float* __restrict__ fout, int M)
{
    __shared__ ushort As[64 * LDA];
    const int t = threadIdx.x;
    const int w = t >> 6;
    const int l = t & 63;
    const int wr = w >> 1, wc = w & 1;
    const int l15 = l & 15, l4 = l >> 4;
    const int brow = blockIdx.x * 64;

    f32x4 acc[2][4];
#pragma unroll
    for (int i = 0; i < 2; ++i)
#pragma unroll
        for (int j = 0; j < 4; ++j) acc[i][j] = (f32x4){0.f, 0.f, 0.f, 0.f};

    gemm_core(As, acc, A0, WT0, A1, WT1, nullptr, nullptr, 2, brow, M);

    __syncthreads();
#pragma unroll
    for (int mi = 0; mi < 2; ++mi) {
#pragma unroll
        for (int ni = 0; ni < 4; ++ni) {
            int col = wc * 64 + ni * 16 + l15;
            float bb = bias[col];
#pragma unroll
            for (int r = 0; r < 4; ++r) {
                int row = wr * 32 + mi * 16 + l4 * 4 + r;
                float v = acc[mi][ni][r] + bb;
                v = v > 0.f ? v : 0.01f * v;
                As[row * LDA + col] = f2b(v);
            }
        }
    }
    __syncthreads();
    f32x4 a2c[2];
    a2c[0] = (f32x4){0.f, 0.f, 0.f, 0.f};
    a2c[1] = (f32x4){0.f, 0.f, 0.f, 0.f};
#pragma unroll
    for (int ks = 0; ks < 4; ++ks) {
        s16x8 af = *(const s16x8*)&As[(w * 16 + l15) * LDA + ks * 32 + l4 * 8];
#pragma unroll
        for (int ni = 0; ni < 2; ++ni) {
            s16x8 bf = *(const s16x8*)&linWT[(size_t)(ni * 16 + l15) * D + ks * 32 + l4 * 8];
            a2c[ni] = __builtin_amdgcn_mfma_f32_16x16x32_bf16(af, bf, a2c[ni], 0, 0, 0);
        }
    }
#pragma unroll
    for (int ni = 0; ni < 2; ++ni) {
        int col = ni * 16 + l15;
        float bb = linb[col];
#pragma unroll
        for (int r = 0; r < 4; ++r) {
            int grow = brow + w * 16 + l4 * 4 + r;
            if (grow < M) fout[(size_t)grow * OUTD + col] = a2c[ni][r] + bb;
        }
    }
}

// ---------------- launch ----------------

extern "C" void kernel_launch(void* const* d_in, const int* in_sizes, int n_in,
                              void* d_out, int out_size, void* d_ws, size_t ws_size,
                              hipStream_t stream)
{
    const float* x_author = (const float*)d_in[0];
    const float* x_paper  = (const float*)d_in[1];
    const int*   e_w      = (const int*)d_in[2];   // author -> paper  (r=0)
    const int*   e_wb     = (const int*)d_in[3];   // paper  -> author (r=2)
    const int*   e_c      = (const int*)d_in[4];   // paper  -> paper  (r=1)
    const float* Wl       = (const float*)d_in[5];
    const float* bl       = (const float*)d_in[6];
    const float* Wr       = (const float*)d_in[7];
    const float* linW     = (const float*)d_in[8];
    const float* linb     = (const float*)d_in[9];
    float* out = (float*)d_out;

    // ---- workspace ----
    int* ib = (int*)d_ws;
    int* cursor  = ib;                        // 588 (pad to 640)
    int* rowptr  = ib + 640;                  // 150000
    int* cntd    = ib + 150656;               // 150000
    uint* bucketed = (uint*)(ib + 300672);    // 588*4608 = 2709504
    ushort* csr16  = (ushort*)(ib + 3010176); // 2709504 ushorts (1354752 ints)
    float* bsum_p  = (float*)(ib + 4364928);  // 128
    ushort* ub = (ushort*)(ib + 4365056);
    const size_t R1 = 50001 * (size_t)D;      // padded row count (zero row at ZROW)
    ushort* wt   = ub;                        // 8*16384
    ushort* xb_a = ub + 131072;               // [50001][D]
    ushort* xb_p = xb_a + R1;                 // [50001][D]
    ushort* agg3 = xb_p + R1;                 // [150000][D]
    ushort* p1b  = agg3 + (size_t)NSEG * D;   // [50001][D]
    ushort* a1b  = p1b + R1;                  // [50000][D]
    ushort* g2b  = agg3;   // reuse after gemm_pair consumed agg3

    hipMemsetAsync(cursor, 0, NBK * sizeof(int), stream);

    // K1: cvt | prep | pad rows | bucket-scatter
    front2<<<CVT_BLOCKS + PREP_BLOCKS + SCAT_BLOCKS, 256, 0, stream>>>(
        x_author, x_paper, xb_a, xb_p,
        Wl, Wr, linW, bl, wt, bsum_p, p1b,
        e_w, e_w + NE, e_c, e_c + NE, e_wb, e_wb + NE,
        cursor, bucketed);

    // K2: within-bucket sort -> csr16 + rowptr + cntd
    bucket_sort2<<<NBK, 256, 0, stream>>>(bucketed, cursor, csr16, rowptr, cntd);

    // K3: layer-0 gathers, relation->XCD partitioned (40000 blocks)
    gather3<<<40000, 256, 0, stream>>>(xb_a, xb_p, rowptr, cntd, csr16, agg3);

    // K4: both layer-0 GEMMs
    gemm_pair<<<1564, 256, 0, stream>>>(agg3, xb_p, xb_a, wt, bsum_p, bl, p1b, a1b);

    // K5: layer-1 gather of p1 over written_by
    gather_l1<<<NA * 64 / 256, 256, 0, stream>>>(p1b, rowptr, cntd, csr16, g2b);

    // K6: a2 = lrelu(g2@Wl11 + a1@Wr11 + bl11); out = a2@linW + linb (fused)
    gemm_final<<<(NA + 63) / 64, 256, 0, stream>>>(
        g2b, wt + 5 * DD, a1b, wt + 6 * DD, bl + 4 * D, wt + 7 * DD, linb, out, NA);
}

// Round 13
// 246.002 us; speedup vs baseline: 1.0266x; 1.0266x over previous
//
#include <hip/hip_runtime.h>

#define NA 50000
#define NP 50000
#define NE 800000
#define D 128
#define OUTD 32
#define NSEG 150000
#define DD (D * D)
#define NCH 196        // chunks per relation (4096 edges each)
#define NBK 588        // 3 relations x 196 buckets (dst>>8)
#define CHE 4096       // edges per chunk
#define CAP2 4608      // fixed bucket capacity (mean 4096 + 8 sigma)
#define ZROW 50000     // index of the all-zeros pad row

typedef float f32x4 __attribute__((ext_vector_type(4)));
typedef short s16x8 __attribute__((ext_vector_type(8)));

__device__ __forceinline__ ushort f2b(float f) {
    uint x = __float_as_uint(f);
    x += ((x >> 16) & 1u) + 0x7fffu;   // round-to-nearest-even
    return (ushort)(x >> 16);
}

// ---------------- K1: cvt_x | prep_w | zero-pad rows | bucket-scatter ----------------

#define CVT_BLOCKS 12500   // 3.2M float4
#define PREP_BLOCKS 466    // 465 weight-prep + 1 zero-pad-rows
#define SCAT_BLOCKS NBK

__global__ __launch_bounds__(256) void front2(
    const float* __restrict__ xa, const float* __restrict__ xp,
    ushort* __restrict__ oa, ushort* __restrict__ op,
    const float* __restrict__ Wl, const float* __restrict__ Wr,
    const float* __restrict__ linW, const float* __restrict__ bl,
    ushort* __restrict__ wt, float* __restrict__ bsum_p,
    ushort* __restrict__ p1b,
    const int* __restrict__ sw, const int* __restrict__ dw,
    const int* __restrict__ sc_, const int* __restrict__ dc,
    const int* __restrict__ swb, const int* __restrict__ dwb,
    int* __restrict__ cursor, uint* __restrict__ bucketed)
{
    __shared__ uint recbuf[CHE];       // 16 KB chunk stash
    __shared__ int hist[NCH], gbase[NCH], cnt2[NCH];
    int b = blockIdx.x, t = threadIdx.x;
    if (b < CVT_BLOCKS) {
        int i = b * 256 + t;
        const int per = NA * D / 4;
        const float* src; ushort* dst; int li;
        if (i < per) { src = xa; dst = oa; li = i; }
        else { src = xp; dst = op; li = i - per; }
        float4 v = *(const float4*)&src[(size_t)li * 4];
        ushort4 o;
        o.x = f2b(v.x); o.y = f2b(v.y); o.z = f2b(v.z); o.w = f2b(v.w);
        *(ushort4*)&dst[(size_t)li * 4] = o;
    } else if (b < CVT_BLOCKS + PREP_BLOCKS) {
        int b2 = b - CVT_BLOCKS;
        if (b2 < 448) {
            int job = b2 >> 6;
            int idx = (b2 & 63) * 256 + t;
            int n = idx >> 7, k = idx & 127;
            const float* src;
            float add = 0.f;
            switch (job) {
                case 0: src = Wl + 0 * DD; break;
                case 1: src = Wl + 2 * DD; break;
                case 2: src = Wr + 0 * DD; add = Wr[2 * DD + k * D + n]; break;
                case 3: src = Wl + 1 * DD; break;
                case 4: src = Wr + 1 * DD; break;
                case 5: src = Wl + 4 * DD; break;
                default: src = Wr + 4 * DD; break;
            }
            wt[(size_t)job * DD + idx] = f2b(src[k * D + n] + add);
        } else if (b2 < 464) {
            int idx = (b2 - 448) * 256 + t;    // linW^T: n<32, k<128
            int n = idx >> 7, k = idx & 127;
            wt[(size_t)7 * DD + idx] = f2b(linW[k * OUTD + n]);
        } else if (b2 == 464) {
            if (t < D) bsum_p[t] = bl[t] + bl[2 * D + t];
        } else {
            // zero the pad rows (index ZROW) of oa, op, p1b
            if (t < 64)       ((uint*)(oa + (size_t)ZROW * D))[t] = 0;
            else if (t < 128) ((uint*)(op + (size_t)ZROW * D))[t - 64] = 0;
            else if (t < 192) ((uint*)(p1b + (size_t)ZROW * D))[t - 128] = 0;
        }
    } else {
        int hb = b - CVT_BLOCKS - PREP_BLOCKS;
        int r = hb / NCH, c = hb % NCH;
        const int* sp = (r == 0) ? sw : ((r == 1) ? sc_ : swb);
        const int* dp = (r == 0) ? dw : ((r == 1) ? dc : dwb);
        for (int i = t; i < NCH; i += 256) { hist[i] = 0; cnt2[i] = 0; }
        __syncthreads();
        int base = c * CHE;
#pragma unroll
        for (int i = 0; i < 16; ++i) {
            int e = base + i * 256 + t;
            uint rec = 0xFFFFFFFFu;
            if (e < NE) {
                int d = dp[e], s = sp[e];
                rec = ((uint)d << 16) | (uint)s;
                atomicAdd(&hist[d >> 8], 1);
            }
            recbuf[i * 256 + t] = rec;
        }
        __syncthreads();
        for (int i = t; i < NCH; i += 256)
            gbase[i] = (r * NCH + i) * CAP2 + atomicAdd(&cursor[r * NCH + i], hist[i]);
        __syncthreads();
#pragma unroll
        for (int i = 0; i < 16; ++i) {
            uint rec = recbuf[i * 256 + t];
            if (rec != 0xFFFFFFFFu) {
                int dg = rec >> 24;             // (d>>8), d<50000<2^16
                int rk = atomicAdd(&cnt2[dg], 1);
                bucketed[gbase[dg] + rk] = rec;
            }
        }
    }
}

// ---------------- K2: within-bucket sort -> csr16 + meta(beg,cnt) ----------------
// 1024 threads (r12 had 256 -> only 2.3 waves/CU for 2.4M records)

__global__ __launch_bounds__(1024) void bucket_sort2(
    const uint* __restrict__ bucketed, const int* __restrict__ cursor,
    ushort* __restrict__ csr16, int2* __restrict__ meta)
{
    __shared__ int h[256], bb[256], c3[256];
    int gd = blockIdx.x, t = threadIdx.x;
    int r = gd / NCH, hb = gd % NCH;
    int beg = gd * CAP2;
    int n = cursor[gd];
    if (t < 256) { h[t] = 0; c3[t] = 0; }
    __syncthreads();
    for (int i = t; i < n; i += 1024)
        atomicAdd(&h[(bucketed[beg + i] >> 16) & 255], 1);
    __syncthreads();
    if (t < 64) {
        int carry = 0;
#pragma unroll
        for (int rnd = 0; rnd < 4; ++rnd) {
            int idx = rnd * 64 + t;
            int v = h[idx], x = v;
#pragma unroll
            for (int off = 1; off < 64; off <<= 1) {
                int y = __shfl_up(x, off, 64);
                if (t >= off) x += y;
            }
            bb[idx] = carry + x - v;
            carry += __shfl(x, 63, 64);
        }
    }
    __syncthreads();
    if (t < 256) {
        int dst = hb * 256 + t;
        if (dst < 50000) meta[r * 50000 + dst] = make_int2(beg + bb[t], h[t]);
    }
    for (int i = t; i < n; i += 1024) {
        uint rec = bucketed[beg + i];
        int low = (rec >> 16) & 255;
        int rk = atomicAdd(&c3[low], 1);
        csr16[beg + bb[low] + rk] = (ushort)(rec & 0xffffu);
    }
}

// ---------------- gather-mean (r8 core): zero-row pad + v_dot2_f32_bf16 ----------------

#define DOT2(a, u, m) asm("v_dot2_f32_bf16 %0, %1, %2, %0" : "+v"(a) : "v"(u), "v"(m))

__device__ __forceinline__ void gather_node(
    const ushort* __restrict__ x, const ushort* __restrict__ bk, int n,
    int l, int g, int c, ushort* __restrict__ outp)
{
    float acc[8];
#pragma unroll
    for (int k = 0; k < 8; ++k) acc[k] = 0.f;
    const uint mlo = 0x00003f80u;   // bf16 (1.0, 0)
    const uint mhi = 0x3f800000u;   // bf16 (0, 1.0)
    const uint cb = (uint)c * 16;   // byte offset within row

    for (int base = 0; base < n; base += 64) {
        int rem = n - base;
        int m = rem > 64 ? 64 : rem;
        int idx = (l < m) ? (int)bk[base + l] : ZROW;
        int mceil = (m + 3) & ~3;
#pragma unroll 4
        for (int j = 0; j < mceil; j += 4) {
            int row = __shfl(idx, j + g, 64);
            uint4 u = *(const uint4*)((const char*)x + (((uint)row << 8) + cb));
            DOT2(acc[0], u.x, mlo); DOT2(acc[1], u.x, mhi);
            DOT2(acc[2], u.y, mlo); DOT2(acc[3], u.y, mhi);
            DOT2(acc[4], u.z, mlo); DOT2(acc[5], u.z, mhi);
            DOT2(acc[6], u.w, mlo); DOT2(acc[7], u.w, mhi);
        }
    }
#pragma unroll
    for (int k = 0; k < 8; ++k) {
        acc[k] += __shfl_xor(acc[k], 16, 64);
        acc[k] += __shfl_xor(acc[k], 32, 64);
    }
    if (g == 0) {
        float scl = (n > 0) ? 1.0f / (float)n : 0.f;
        uint4 o;
        o.x = (uint)f2b(acc[0] * scl) | ((uint)f2b(acc[1] * scl) << 16);
        o.y = (uint)f2b(acc[2] * scl) | ((uint)f2b(acc[3] * scl) << 16);
        o.z = (uint)f2b(acc[4] * scl) | ((uint)f2b(acc[5] * scl) << 16);
        o.w = (uint)f2b(acc[6] * scl) | ((uint)f2b(acc[7] * scl) << 16);
        *(uint4*)&outp[c * 8] = o;
    }
}

__global__ __launch_bounds__(256) void gather3(
    const ushort* __restrict__ xa, const ushort* __restrict__ xp,
    const int2* __restrict__ meta, const ushort* __restrict__ csr16,
    ushort* __restrict__ agg3)
{
    int wid = (blockIdx.x * 256 + threadIdx.x) >> 6;
    if (wid >= NSEG) return;
    const ushort* x = (wid < 50000) ? xa : xp;
    int l = threadIdx.x & 63;
    int2 m = meta[wid];
    int beg = __builtin_amdgcn_readfirstlane(m.x);
    int n = __builtin_amdgcn_readfirstlane(m.y);
    gather_node(x, csr16 + beg, n, l, l >> 4, l & 15,
                agg3 + (size_t)wid * D);
}

__global__ __launch_bounds__(256) void gather_l1(
    const ushort* __restrict__ x, const int2* __restrict__ meta,
    const ushort* __restrict__ csr16, ushort* __restrict__ out)
{
    int wid = (blockIdx.x * 256 + threadIdx.x) >> 6;
    if (wid >= NA) return;
    int l = threadIdx.x & 63;
    int2 m = meta[100000 + wid];
    int beg = __builtin_amdgcn_readfirstlane(m.x);
    int n = __builtin_amdgcn_readfirstlane(m.y);
    gather_node(x, csr16 + beg, n, l, l >> 4, l & 15,
                out + (size_t)wid * D);
}

// ---------------- MFMA bf16 GEMM core ----------------

#define LDA 136

__device__ __forceinline__ void gemm_core(
    ushort* As, f32x4 (&acc)[2][4],
    const ushort* __restrict__ A0, const ushort* __restrict__ WT0,
    const ushort* __restrict__ A1, const ushort* __restrict__ WT1,
    const ushort* __restrict__ A2, const ushort* __restrict__ WT2,
    int nseg, int brow, int M)
{
    const int t = threadIdx.x;
    const int w = t >> 6;
    const int l = t & 63;
    const int wr = w >> 1, wc = w & 1;
    const int l15 = l & 15, l4 = l >> 4;

    for (int s = 0; s < nseg; ++s) {
        const ushort* A = (s == 0) ? A0 : ((s == 1) ? A1 : A2);
        const ushort* WT = (s == 0) ? WT0 : ((s == 1) ? WT1 : WT2);

        if (s) __syncthreads();
#pragma unroll
        for (int it = 0; it < 4; ++it) {
            int f = it * 256 + t;
            int row = f >> 4, cc = f & 15;
            int grow = brow + row;
            float4 v = make_float4(0.f, 0.f, 0.f, 0.f);
            if (grow < M) v = *(const float4*)&A[(size_t)grow * D + cc * 8];
            *(float4*)&As[row * LDA + cc * 8] = v;
        }
        s16x8 Bf[4][4];
#pragma unroll
        for (int ni = 0; ni < 4; ++ni)
#pragma unroll
            for (int ks = 0; ks < 4; ++ks)
                Bf[ni][ks] = *(const s16x8*)&WT[(size_t)(wc * 64 + ni * 16 + l15) * D + ks * 32 + l4 * 8];
        __syncthreads();

#pragma unroll
        for (int ks = 0; ks < 4; ++ks) {
            s16x8 af[2];
#pragma unroll
            for (int mi = 0; mi < 2; ++mi)
                af[mi] = *(const s16x8*)&As[(wr * 32 + mi * 16 + l15) * LDA + ks * 32 + l4 * 8];
#pragma unroll
            for (int mi = 0; mi < 2; ++mi)
#pragma unroll
                for (int ni = 0; ni < 4; ++ni)
                    acc[mi][ni] = __builtin_amdgcn_mfma_f32_16x16x32_bf16(
                        af[mi], Bf[ni][ks], acc[mi][ni], 0, 0, 0);
        }
    }
}

// both layer-0 GEMMs in one dispatch
__global__ __launch_bounds__(256) void gemm_pair(
    const ushort* __restrict__ agg3, const ushort* __restrict__ xb_p,
    const ushort* __restrict__ xb_a, const ushort* __restrict__ wt,
    const float* __restrict__ bsum_p, const float* __restrict__ bl,
    ushort* __restrict__ p1b, ushort* __restrict__ a1b)
{
    __shared__ ushort As[64 * LDA];
    const int t = threadIdx.x;
    const int w = t >> 6;
    const int l = t & 63;
    const int wr = w >> 1, wc = w & 1;
    const int l15 = l & 15, l4 = l >> 4;

    f32x4 acc[2][4];
#pragma unroll
    for (int i = 0; i < 2; ++i)
#pragma unroll
        for (int j = 0; j < 4; ++j) acc[i][j] = (f32x4){0.f, 0.f, 0.f, 0.f};

    bool isP = blockIdx.x < 782;
    int bIdx = isP ? blockIdx.x : blockIdx.x - 782;
    int brow = bIdx * 64;
    const float* bias;
    ushort* C;
    if (isP) {
        gemm_core(As, acc, agg3, wt + 0 * DD, agg3 + (size_t)50000 * D, wt + 1 * DD,
                  xb_p, wt + 2 * DD, 3, brow, NP);
        bias = bsum_p; C = p1b;
    } else {
        gemm_core(As, acc, agg3 + (size_t)100000 * D, wt + 3 * DD, xb_a, wt + 4 * DD,
                  nullptr, nullptr, 2, brow, NA);
        bias = bl + 1 * D; C = a1b;
    }

#pragma unroll
    for (int mi = 0; mi < 2; ++mi) {
#pragma unroll
        for (int ni = 0; ni < 4; ++ni) {
            int col = wc * 64 + ni * 16 + l15;
            float bb = bias[col];
#pragma unroll
            for (int r = 0; r < 4; ++r) {
                int grow = brow + wr * 32 + mi * 16 + l4 * 4 + r;
                if (grow >= 50000) continue;
                float v = acc[mi][ni][r] + bb;
                v = v > 0.f ? v : 0.01f * v;
                C[(size_t)grow * D + col] = f2b(v);
            }
        }
    }
}

// layer-1 author GEMM with fused final projection
__global__ __launch_bounds__(256) void gemm_final(
    const ushort* __restrict__ A0, const ushort* __restrict__ WT0,
    const ushort* __restrict__ A1, const ushort* __restrict__ WT1,
    const float* __restrict__ bias,
    const ushort* __restrict__ linWT, const float* __restrict__ linb,
    float* __restrict__ fout, int M)
{
    __shared__ ushort As[64 * LDA];
    const int t = threadIdx.x;
    const int w = t >> 6;
    const int l = t & 63;
    const int wr = w >> 1, wc = w & 1;
    const int l15 = l & 15, l4 = l >> 4;
    const int brow = blockIdx.x * 64;

    f32x4 acc[2][4];
#pragma unroll
    for (int i = 0; i < 2; ++i)
#pragma unroll
        for (int j = 0; j < 4; ++j) acc[i][j] = (f32x4){0.f, 0.f, 0.f, 0.f};

    gemm_core(As, acc, A0, WT0, A1, WT1, nullptr, nullptr, 2, brow, M);

    __syncthreads();
#pragma unroll
    for (int mi = 0; mi < 2; ++mi) {
#pragma unroll
        for (int ni = 0; ni < 4; ++ni) {
            int col = wc * 64 + ni * 16 + l15;
            float bb = bias[col];
#pragma unroll
            for (int r = 0; r < 4; ++r) {
                int row = wr * 32 + mi * 16 + l4 * 4 + r;
                float v = acc[mi][ni][r] + bb;
                v = v > 0.f ? v : 0.01f * v;
                As[row * LDA + col] = f2b(v);
            }
        }
    }
    __syncthreads();
    f32x4 a2c[2];
    a2c[0] = (f32x4){0.f, 0.f, 0.f, 0.f};
    a2c[1] = (f32x4){0.f, 0.f, 0.f, 0.f};
#pragma unroll
    for (int ks = 0; ks < 4; ++ks) {
        s16x8 af = *(const s16x8*)&As[(w * 16 + l15) * LDA + ks * 32 + l4 * 8];
#pragma unroll
        for (int ni = 0; ni < 2; ++ni) {
            s16x8 bf = *(const s16x8*)&linWT[(size_t)(ni * 16 + l15) * D + ks * 32 + l4 * 8];
            a2c[ni] = __builtin_amdgcn_mfma_f32_16x16x32_bf16(af, bf, a2c[ni], 0, 0, 0);
        }
    }
#pragma unroll
    for (int ni = 0; ni < 2; ++ni) {
        int col = ni * 16 + l15;
        float bb = linb[col];
#pragma unroll
        for (int r = 0; r < 4; ++r) {
            int grow = brow + w * 16 + l4 * 4 + r;
            if (grow < M) fout[(size_t)grow * OUTD + col] = a2c[ni][r] + bb;
        }
    }
}

// ---------------- launch ----------------

extern "C" void kernel_launch(void* const* d_in, const int* in_sizes, int n_in,
                              void* d_out, int out_size, void* d_ws, size_t ws_size,
                              hipStream_t stream)
{
    const float* x_author = (const float*)d_in[0];
    const float* x_paper  = (const float*)d_in[1];
    const int*   e_w      = (const int*)d_in[2];   // author -> paper  (r=0)
    const int*   e_wb     = (const int*)d_in[3];   // paper  -> author (r=2)
    const int*   e_c      = (const int*)d_in[4];   // paper  -> paper  (r=1)
    const float* Wl       = (const float*)d_in[5];
    const float* bl       = (const float*)d_in[6];
    const float* Wr       = (const float*)d_in[7];
    const float* linW     = (const float*)d_in[8];
    const float* linb     = (const float*)d_in[9];
    float* out = (float*)d_out;

    // ---- workspace ----
    int* ib = (int*)d_ws;
    int* cursor  = ib;                        // 588 (pad to 640)
    int2* meta   = (int2*)(ib + 640);         // 150000 int2 = 300000 ints
    uint* bucketed = (uint*)(ib + 300672);    // 588*4608 = 2709504
    ushort* csr16  = (ushort*)(ib + 3010176); // 2709504 ushorts (1354752 ints)
    float* bsum_p  = (float*)(ib + 4364928);  // 128
    ushort* ub = (ushort*)(ib + 4365056);
    const size_t R1 = 50001 * (size_t)D;      // padded row count (zero row at ZROW)
    ushort* wt   = ub;                        // 8*16384
    ushort* xb_a = ub + 131072;               // [50001][D]
    ushort* xb_p = xb_a + R1;                 // [50001][D]
    ushort* agg3 = xb_p + R1;                 // [150000][D]
    ushort* p1b  = agg3 + (size_t)NSEG * D;   // [50001][D]
    ushort* a1b  = p1b + R1;                  // [50000][D]
    ushort* g2b  = agg3;   // reuse after gemm_pair consumed agg3

    hipMemsetAsync(cursor, 0, NBK * sizeof(int), stream);

    // K1: cvt | prep | pad rows | bucket-scatter
    front2<<<CVT_BLOCKS + PREP_BLOCKS + SCAT_BLOCKS, 256, 0, stream>>>(
        x_author, x_paper, xb_a, xb_p,
        Wl, Wr, linW, bl, wt, bsum_p, p1b,
        e_w, e_w + NE, e_c, e_c + NE, e_wb, e_wb + NE,
        cursor, bucketed);

    // K2: within-bucket sort -> csr16 + meta (1024 threads: 4x wave count)
    bucket_sort2<<<NBK, 1024, 0, stream>>>(bucketed, cursor, csr16, meta);

    // K3: layer-0 gathers (150000 waves, r8 core, simple mapping)
    gather3<<<NSEG * 64 / 256, 256, 0, stream>>>(xb_a, xb_p, meta, csr16, agg3);

    // K4: both layer-0 GEMMs
    gemm_pair<<<1564, 256, 0, stream>>>(agg3, xb_p, xb_a, wt, bsum_p, bl, p1b, a1b);

    // K5: layer-1 gather of p1 over written_by
    gather_l1<<<NA * 64 / 256, 256, 0, stream>>>(p1b, meta, csr16, g2b);

    // K6: a2 = lrelu(g2@Wl11 + a1@Wr11 + bl11); out = a2@linW + linb (fused)
    gemm_final<<<(NA + 63) / 64, 256, 0, stream>>>(
        g2b, wt + 5 * DD, a1b, wt + 6 * DD, bl + 4 * D, wt + 7 * DD, linb, out, NA);
}

// Round 14
// 232.918 us; speedup vs baseline: 1.0843x; 1.0562x over previous
//
#include <hip/hip_runtime.h>

#define NA 50000
#define NP 50000
#define NE 800000
#define D 128
#define OUTD 32
#define NSEG 150000
#define DD (D * D)
#define NCH 196        // chunks per relation (4096 edges each)
#define NBK 588        // 3 relations x 196 buckets (dst>>8)
#define CHE 4096       // edges per chunk
#define CAP2 4608      // fixed bucket capacity (mean 4096 + 8 sigma)
#define ZROW 50000     // index of the all-zeros pad row

typedef float f32x4 __attribute__((ext_vector_type(4)));
typedef short s16x8 __attribute__((ext_vector_type(8)));

__device__ __forceinline__ ushort f2b(float f) {
    uint x = __float_as_uint(f);
    x += ((x >> 16) & 1u) + 0x7fffu;   // round-to-nearest-even
    return (ushort)(x >> 16);
}

// ---------------- K1: cvt_x | prep_w | zero-pad rows | bucket-scatter ----------------
// Scatter phase now builds a bucket-sorted copy of the chunk in LDS and writes
// bucketed[] out in LINEAR order -> consecutive lanes hit consecutive global
// addresses within each ~21-entry bucket run (coalesced bursts instead of one
// 32B sector per 4B record).

#define CVT_BLOCKS 12500   // 3.2M float4
#define PREP_BLOCKS 466    // 465 weight-prep + 1 zero-pad-rows
#define SCAT_BLOCKS NBK

__global__ __launch_bounds__(256) void front2(
    const float* __restrict__ xa, const float* __restrict__ xp,
    ushort* __restrict__ oa, ushort* __restrict__ op,
    const float* __restrict__ Wl, const float* __restrict__ Wr,
    const float* __restrict__ linW, const float* __restrict__ bl,
    ushort* __restrict__ wt, float* __restrict__ bsum_p,
    ushort* __restrict__ p1b,
    const int* __restrict__ sw, const int* __restrict__ dw,
    const int* __restrict__ sc_, const int* __restrict__ dc,
    const int* __restrict__ swb, const int* __restrict__ dwb,
    int* __restrict__ cursor, uint* __restrict__ bucketed)
{
    __shared__ uint srt[CHE];                    // bucket-sorted chunk (16 KB)
    __shared__ int hist[NCH], lb[NCH], goff[NCH], cnt2[NCH];
    __shared__ int tot;
    int b = blockIdx.x, t = threadIdx.x;
    if (b < CVT_BLOCKS) {
        int i = b * 256 + t;
        const int per = NA * D / 4;
        const float* src; ushort* dst; int li;
        if (i < per) { src = xa; dst = oa; li = i; }
        else { src = xp; dst = op; li = i - per; }
        float4 v = *(const float4*)&src[(size_t)li * 4];
        ushort4 o;
        o.x = f2b(v.x); o.y = f2b(v.y); o.z = f2b(v.z); o.w = f2b(v.w);
        *(ushort4*)&dst[(size_t)li * 4] = o;
    } else if (b < CVT_BLOCKS + PREP_BLOCKS) {
        int b2 = b - CVT_BLOCKS;
        if (b2 < 448) {
            int job = b2 >> 6;
            int idx = (b2 & 63) * 256 + t;
            int n = idx >> 7, k = idx & 127;
            const float* src;
            float add = 0.f;
            switch (job) {
                case 0: src = Wl + 0 * DD; break;
                case 1: src = Wl + 2 * DD; break;
                case 2: src = Wr + 0 * DD; add = Wr[2 * DD + k * D + n]; break;
                case 3: src = Wl + 1 * DD; break;
                case 4: src = Wr + 1 * DD; break;
                case 5: src = Wl + 4 * DD; break;
                default: src = Wr + 4 * DD; break;
            }
            wt[(size_t)job * DD + idx] = f2b(src[k * D + n] + add);
        } else if (b2 < 464) {
            int idx = (b2 - 448) * 256 + t;    // linW^T: n<32, k<128
            int n = idx >> 7, k = idx & 127;
            wt[(size_t)7 * DD + idx] = f2b(linW[k * OUTD + n]);
        } else if (b2 == 464) {
            if (t < D) bsum_p[t] = bl[t] + bl[2 * D + t];
        } else {
            // zero the pad rows (index ZROW) of oa, op, p1b
            if (t < 64)       ((uint*)(oa + (size_t)ZROW * D))[t] = 0;
            else if (t < 128) ((uint*)(op + (size_t)ZROW * D))[t - 64] = 0;
            else if (t < 192) ((uint*)(p1b + (size_t)ZROW * D))[t - 128] = 0;
        }
    } else {
        int hb = b - CVT_BLOCKS - PREP_BLOCKS;
        int r = hb / NCH, c = hb % NCH;
        const int* sp = (r == 0) ? sw : ((r == 1) ? sc_ : swb);
        const int* dp = (r == 0) ? dw : ((r == 1) ? dc : dwb);
        for (int i = t; i < NCH; i += 256) { hist[i] = 0; cnt2[i] = 0; }
        __syncthreads();
        int base = c * CHE;
        // pass 1: histogram (edges stay L1/L2-hot for pass 2 re-read)
#pragma unroll
        for (int i = 0; i < 16; ++i) {
            int e = base + i * 256 + t;
            if (e < NE) atomicAdd(&hist[dp[e] >> 8], 1);
        }
        __syncthreads();
        // exclusive scan hist -> lb (local sorted base per bucket)
        if (t < 64) {
            int carry = 0;
#pragma unroll
            for (int rnd = 0; rnd < 4; ++rnd) {
                int idx = rnd * 64 + t;
                int v = (idx < NCH) ? hist[idx] : 0;
                int x = v;
#pragma unroll
                for (int off = 1; off < 64; off <<= 1) {
                    int y = __shfl_up(x, off, 64);
                    if (t >= off) x += y;
                }
                if (idx < NCH) lb[idx] = carry + x - v;
                carry += __shfl(x, 63, 64);
            }
            if (t == 0) tot = carry;
        }
        __syncthreads();
        // reserve global runs; goff[dg] + local_sorted_pos = global index
        for (int i = t; i < NCH; i += 256) {
            int gd = r * NCH + i;
            int g0 = gd * CAP2 + atomicAdd(&cursor[gd], hist[i]);
            goff[i] = g0 - lb[i];
        }
        __syncthreads();
        // pass 2: rank + LDS scatter into sorted position
#pragma unroll
        for (int i = 0; i < 16; ++i) {
            int e = base + i * 256 + t;
            if (e < NE) {
                uint rec = ((uint)dp[e] << 16) | (uint)sp[e];
                int dg = rec >> 24;
                int rk = atomicAdd(&cnt2[dg], 1);
                srt[lb[dg] + rk] = rec;
            }
        }
        __syncthreads();
        // pass 3: coalesced write-out (consecutive lanes -> consecutive addrs)
        int T = tot;
        for (int i = t; i < T; i += 256) {
            uint rec = srt[i];
            bucketed[goff[rec >> 24] + i] = rec;
        }
    }
}

// ---------------- K2: within-bucket sort -> csr16 + meta(beg,cnt) ----------------
// LDS-sorted then coalesced uint write-out (was: 2.4M random 2B sector-writes)

__global__ __launch_bounds__(1024) void bucket_sort2(
    const uint* __restrict__ bucketed, const int* __restrict__ cursor,
    ushort* __restrict__ csr16, int2* __restrict__ meta)
{
    __shared__ int h[256], bb[256], c3[256];
    __shared__ ushort srt16[CAP2];
    int gd = blockIdx.x, t = threadIdx.x;
    int r = gd / NCH, hb = gd % NCH;
    int beg = gd * CAP2;
    int n = cursor[gd];
    if (t < 256) { h[t] = 0; c3[t] = 0; }
    __syncthreads();
    for (int i = t; i < n; i += 1024)
        atomicAdd(&h[(bucketed[beg + i] >> 16) & 255], 1);
    __syncthreads();
    if (t < 64) {
        int carry = 0;
#pragma unroll
        for (int rnd = 0; rnd < 4; ++rnd) {
            int idx = rnd * 64 + t;
            int v = h[idx], x = v;
#pragma unroll
            for (int off = 1; off < 64; off <<= 1) {
                int y = __shfl_up(x, off, 64);
                if (t >= off) x += y;
            }
            bb[idx] = carry + x - v;
            carry += __shfl(x, 63, 64);
        }
    }
    __syncthreads();
    if (t < 256) {
        int dst = hb * 256 + t;
        if (dst < 50000) meta[r * 50000 + dst] = make_int2(beg + bb[t], h[t]);
    }
    for (int i = t; i < n; i += 1024) {
        uint rec = bucketed[beg + i];
        int low = (rec >> 16) & 255;
        int rk = atomicAdd(&c3[low], 1);
        srt16[bb[low] + rk] = (ushort)(rec & 0xffffu);
    }
    __syncthreads();
    // coalesced copy-out, 2 ushorts per store (beg is even; slack never read)
    int nu = (n + 1) >> 1;
    uint* dst32 = (uint*)(csr16 + beg);
    const uint* src32 = (const uint*)srt16;
    for (int i = t; i < nu; i += 1024)
        dst32[i] = src32[i];
}

// ---------------- gather-mean (r8 core): zero-row pad + v_dot2_f32_bf16 ----------------

#define DOT2(a, u, m) asm("v_dot2_f32_bf16 %0, %1, %2, %0" : "+v"(a) : "v"(u), "v"(m))

__device__ __forceinline__ void gather_node(
    const ushort* __restrict__ x, const ushort* __restrict__ bk, int n,
    int l, int g, int c, ushort* __restrict__ outp)
{
    float acc[8];
#pragma unroll
    for (int k = 0; k < 8; ++k) acc[k] = 0.f;
    const uint mlo = 0x00003f80u;   // bf16 (1.0, 0)
    const uint mhi = 0x3f800000u;   // bf16 (0, 1.0)
    const uint cb = (uint)c * 16;   // byte offset within row

    for (int base = 0; base < n; base += 64) {
        int rem = n - base;
        int m = rem > 64 ? 64 : rem;
        int idx = (l < m) ? (int)bk[base + l] : ZROW;
        int mceil = (m + 3) & ~3;
#pragma unroll 4
        for (int j = 0; j < mceil; j += 4) {
            int row = __shfl(idx, j + g, 64);
            uint4 u = *(const uint4*)((const char*)x + (((uint)row << 8) + cb));
            DOT2(acc[0], u.x, mlo); DOT2(acc[1], u.x, mhi);
            DOT2(acc[2], u.y, mlo); DOT2(acc[3], u.y, mhi);
            DOT2(acc[4], u.z, mlo); DOT2(acc[5], u.z, mhi);
            DOT2(acc[6], u.w, mlo); DOT2(acc[7], u.w, mhi);
        }
    }
#pragma unroll
    for (int k = 0; k < 8; ++k) {
        acc[k] += __shfl_xor(acc[k], 16, 64);
        acc[k] += __shfl_xor(acc[k], 32, 64);
    }
    if (g == 0) {
        float scl = (n > 0) ? 1.0f / (float)n : 0.f;
        uint4 o;
        o.x = (uint)f2b(acc[0] * scl) | ((uint)f2b(acc[1] * scl) << 16);
        o.y = (uint)f2b(acc[2] * scl) | ((uint)f2b(acc[3] * scl) << 16);
        o.z = (uint)f2b(acc[4] * scl) | ((uint)f2b(acc[5] * scl) << 16);
        o.w = (uint)f2b(acc[6] * scl) | ((uint)f2b(acc[7] * scl) << 16);
        *(uint4*)&outp[c * 8] = o;
    }
}

__global__ __launch_bounds__(256) void gather3(
    const ushort* __restrict__ xa, const ushort* __restrict__ xp,
    const int2* __restrict__ meta, const ushort* __restrict__ csr16,
    ushort* __restrict__ agg3)
{
    int wid = (blockIdx.x * 256 + threadIdx.x) >> 6;
    if (wid >= NSEG) return;
    const ushort* x = (wid < 50000) ? xa : xp;
    int l = threadIdx.x & 63;
    int2 m = meta[wid];
    int beg = __builtin_amdgcn_readfirstlane(m.x);
    int n = __builtin_amdgcn_readfirstlane(m.y);
    gather_node(x, csr16 + beg, n, l, l >> 4, l & 15,
                agg3 + (size_t)wid * D);
}

__global__ __launch_bounds__(256) void gather_l1(
    const ushort* __restrict__ x, const int2* __restrict__ meta,
    const ushort* __restrict__ csr16, ushort* __restrict__ out)
{
    int wid = (blockIdx.x * 256 + threadIdx.x) >> 6;
    if (wid >= NA) return;
    int l = threadIdx.x & 63;
    int2 m = meta[100000 + wid];
    int beg = __builtin_amdgcn_readfirstlane(m.x);
    int n = __builtin_amdgcn_readfirstlane(m.y);
    gather_node(x, csr16 + beg, n, l, l >> 4, l & 15,
                out + (size_t)wid * D);
}

// ---------------- MFMA bf16 GEMM core ----------------

#define LDA 136

__device__ __forceinline__ void gemm_core(
    ushort* As, f32x4 (&acc)[2][4],
    const ushort* __restrict__ A0, const ushort* __restrict__ WT0,
    const ushort* __restrict__ A1, const ushort* __restrict__ WT1,
    const ushort* __restrict__ A2, const ushort* __restrict__ WT2,
    int nseg, int brow, int M)
{
    const int t = threadIdx.x;
    const int w = t >> 6;
    const int l = t & 63;
    const int wr = w >> 1, wc = w & 1;
    const int l15 = l & 15, l4 = l >> 4;

    for (int s = 0; s < nseg; ++s) {
        const ushort* A = (s == 0) ? A0 : ((s == 1) ? A1 : A2);
        const ushort* WT = (s == 0) ? WT0 : ((s == 1) ? WT1 : WT2);

        if (s) __syncthreads();
#pragma unroll
        for (int it = 0; it < 4; ++it) {
            int f = it * 256 + t;
            int row = f >> 4, cc = f & 15;
            int grow = brow + row;
            float4 v = make_float4(0.f, 0.f, 0.f, 0.f);
            if (grow < M) v = *(const float4*)&A[(size_t)grow * D + cc * 8];
            *(float4*)&As[row * LDA + cc * 8] = v;
        }
        s16x8 Bf[4][4];
#pragma unroll
        for (int ni = 0; ni < 4; ++ni)
#pragma unroll
            for (int ks = 0; ks < 4; ++ks)
                Bf[ni][ks] = *(const s16x8*)&WT[(size_t)(wc * 64 + ni * 16 + l15) * D + ks * 32 + l4 * 8];
        __syncthreads();

#pragma unroll
        for (int ks = 0; ks < 4; ++ks) {
            s16x8 af[2];
#pragma unroll
            for (int mi = 0; mi < 2; ++mi)
                af[mi] = *(const s16x8*)&As[(wr * 32 + mi * 16 + l15) * LDA + ks * 32 + l4 * 8];
#pragma unroll
            for (int mi = 0; mi < 2; ++mi)
#pragma unroll
                for (int ni = 0; ni < 4; ++ni)
                    acc[mi][ni] = __builtin_amdgcn_mfma_f32_16x16x32_bf16(
                        af[mi], Bf[ni][ks], acc[mi][ni], 0, 0, 0);
        }
    }
}

// both layer-0 GEMMs in one dispatch
__global__ __launch_bounds__(256) void gemm_pair(
    const ushort* __restrict__ agg3, const ushort* __restrict__ xb_p,
    const ushort* __restrict__ xb_a, const ushort* __restrict__ wt,
    const float* __restrict__ bsum_p, const float* __restrict__ bl,
    ushort* __restrict__ p1b, ushort* __restrict__ a1b)
{
    __shared__ ushort As[64 * LDA];
    const int t = threadIdx.x;
    const int w = t >> 6;
    const int l = t & 63;
    const int wr = w >> 1, wc = w & 1;
    const int l15 = l & 15, l4 = l >> 4;

    f32x4 acc[2][4];
#pragma unroll
    for (int i = 0; i < 2; ++i)
#pragma unroll
        for (int j = 0; j < 4; ++j) acc[i][j] = (f32x4){0.f, 0.f, 0.f, 0.f};

    bool isP = blockIdx.x < 782;
    int bIdx = isP ? blockIdx.x : blockIdx.x - 782;
    int brow = bIdx * 64;
    const float* bias;
    ushort* C;
    if (isP) {
        gemm_core(As, acc, agg3, wt + 0 * DD, agg3 + (size_t)50000 * D, wt + 1 * DD,
                  xb_p, wt + 2 * DD, 3, brow, NP);
        bias = bsum_p; C = p1b;
    } else {
        gemm_core(As, acc, agg3 + (size_t)100000 * D, wt + 3 * DD, xb_a, wt + 4 * DD,
                  nullptr, nullptr, 2, brow, NA);
        bias = bl + 1 * D; C = a1b;
    }

#pragma unroll
    for (int mi = 0; mi < 2; ++mi) {
#pragma unroll
        for (int ni = 0; ni < 4; ++ni) {
            int col = wc * 64 + ni * 16 + l15;
            float bb = bias[col];
#pragma unroll
            for (int r = 0; r < 4; ++r) {
                int grow = brow + wr * 32 + mi * 16 + l4 * 4 + r;
                if (grow >= 50000) continue;
                float v = acc[mi][ni][r] + bb;
                v = v > 0.f ? v : 0.01f * v;
                C[(size_t)grow * D + col] = f2b(v);
            }
        }
    }
}

// layer-1 author GEMM with fused final projection
__global__ __launch_bounds__(256) void gemm_final(
    const ushort* __restrict__ A0, const ushort* __restrict__ WT0,
    const ushort* __restrict__ A1, const ushort* __restrict__ WT1,
    const float* __restrict__ bias,
    const ushort* __restrict__ linWT, const float* __restrict__ linb,
    float* __restrict__ fout, int M)
{
    __shared__ ushort As[64 * LDA];
    const int t = threadIdx.x;
    const int w = t >> 6;
    const int l = t & 63;
    const int wr = w >> 1, wc = w & 1;
    const int l15 = l & 15, l4 = l >> 4;
    const int brow = blockIdx.x * 64;

    f32x4 acc[2][4];
#pragma unroll
    for (int i = 0; i < 2; ++i)
#pragma unroll
        for (int j = 0; j < 4; ++j) acc[i][j] = (f32x4){0.f, 0.f, 0.f, 0.f};

    gemm_core(As, acc, A0, WT0, A1, WT1, nullptr, nullptr, 2, brow, M);

    __syncthreads();
#pragma unroll
    for (int mi = 0; mi < 2; ++mi) {
#pragma unroll
        for (int ni = 0; ni < 4; ++ni) {
            int col = wc * 64 + ni * 16 + l15;
            float bb = bias[col];
#pragma unroll
            for (int r = 0; r < 4; ++r) {
                int row = wr * 32 + mi * 16 + l4 * 4 + r;
                float v = acc[mi][ni][r] + bb;
                v = v > 0.f ? v : 0.01f * v;
                As[row * LDA + col] = f2b(v);
            }
        }
    }
    __syncthreads();
    f32x4 a2c[2];
    a2c[0] = (f32x4){0.f, 0.f, 0.f, 0.f};
    a2c[1] = (f32x4){0.f, 0.f, 0.f, 0.f};
#pragma unroll
    for (int ks = 0; ks < 4; ++ks) {
        s16x8 af = *(const s16x8*)&As[(w * 16 + l15) * LDA + ks * 32 + l4 * 8];
#pragma unroll
        for (int ni = 0; ni < 2; ++ni) {
            s16x8 bf = *(const s16x8*)&linWT[(size_t)(ni * 16 + l15) * D + ks * 32 + l4 * 8];
            a2c[ni] = __builtin_amdgcn_mfma_f32_16x16x32_bf16(af, bf, a2c[ni], 0, 0, 0);
        }
    }
#pragma unroll
    for (int ni = 0; ni < 2; ++ni) {
        int col = ni * 16 + l15;
        float bb = linb[col];
#pragma unroll
        for (int r = 0; r < 4; ++r) {
            int grow = brow + w * 16 + l4 * 4 + r;
            if (grow < M) fout[(size_t)grow * OUTD + col] = a2c[ni][r] + bb;
        }
    }
}

// ---------------- launch ----------------

extern "C" void kernel_launch(void* const* d_in, const int* in_sizes, int n_in,
                              void* d_out, int out_size, void* d_ws, size_t ws_size,
                              hipStream_t stream)
{
    const float* x_author = (const float*)d_in[0];
    const float* x_paper  = (const float*)d_in[1];
    const int*   e_w      = (const int*)d_in[2];   // author -> paper  (r=0)
    const int*   e_wb     = (const int*)d_in[3];   // paper  -> author (r=2)
    const int*   e_c      = (const int*)d_in[4];   // paper  -> paper  (r=1)
    const float* Wl       = (const float*)d_in[5];
    const float* bl       = (const float*)d_in[6];
    const float* Wr       = (const float*)d_in[7];
    const float* linW     = (const float*)d_in[8];
    const float* linb     = (const float*)d_in[9];
    float* out = (float*)d_out;

    // ---- workspace ----
    int* ib = (int*)d_ws;
    int* cursor  = ib;                        // 588 (pad to 640)
    int2* meta   = (int2*)(ib + 640);         // 150000 int2 = 300000 ints
    uint* bucketed = (uint*)(ib + 300672);    // 588*4608 = 2709504
    ushort* csr16  = (ushort*)(ib + 3010176); // 2709504 ushorts (1354752 ints)
    float* bsum_p  = (float*)(ib + 4364928);  // 128
    ushort* ub = (ushort*)(ib + 4365056);
    const size_t R1 = 50001 * (size_t)D;      // padded row count (zero row at ZROW)
    ushort* wt   = ub;                        // 8*16384
    ushort* xb_a = ub + 131072;               // [50001][D]
    ushort* xb_p = xb_a + R1;                 // [50001][D]
    ushort* agg3 = xb_p + R1;                 // [150000][D]
    ushort* p1b  = agg3 + (size_t)NSEG * D;   // [50001][D]
    ushort* a1b  = p1b + R1;                  // [50000][D]
    ushort* g2b  = agg3;   // reuse after gemm_pair consumed agg3

    hipMemsetAsync(cursor, 0, NBK * sizeof(int), stream);

    // K1: cvt | prep | pad rows | bucket-scatter (LDS-sorted coalesced write-out)
    front2<<<CVT_BLOCKS + PREP_BLOCKS + SCAT_BLOCKS, 256, 0, stream>>>(
        x_author, x_paper, xb_a, xb_p,
        Wl, Wr, linW, bl, wt, bsum_p, p1b,
        e_w, e_w + NE, e_c, e_c + NE, e_wb, e_wb + NE,
        cursor, bucketed);

    // K2: within-bucket sort -> csr16 + meta (LDS-sorted coalesced write-out)
    bucket_sort2<<<NBK, 1024, 0, stream>>>(bucketed, cursor, csr16, meta);

    // K3: layer-0 gathers (150000 waves, r8 core)
    gather3<<<NSEG * 64 / 256, 256, 0, stream>>>(xb_a, xb_p, meta, csr16, agg3);

    // K4: both layer-0 GEMMs
    gemm_pair<<<1564, 256, 0, stream>>>(agg3, xb_p, xb_a, wt, bsum_p, bl, p1b, a1b);

    // K5: layer-1 gather of p1 over written_by
    gather_l1<<<NA * 64 / 256, 256, 0, stream>>>(p1b, meta, csr16, g2b);

    // K6: a2 = lrelu(g2@Wl11 + a1@Wr11 + bl11); out = a2@linW + linb (fused)
    gemm_final<<<(NA + 63) / 64, 256, 0, stream>>>(
        g2b, wt + 5 * DD, a1b, wt + 6 * DD, bl + 4 * D, wt + 7 * DD, linb, out, NA);
}